// Round 12
// baseline (261.875 us; speedup 1.0000x reference)
//
#include <hip/hip_runtime.h>
#include <hip/hip_bf16.h>

#define SEQ    576
#define DIM    640
#define HEADS  8
#define HD     80          // DIM / HEADS
#define NF     4
#define NB     12          // 3 * NF
#define M_TOT  (NB * SEQ)  // 6912
#define SCALE  0.11180339887498949f   // 1/sqrt(80)
#define LOG2E  1.4426950408889634f

typedef __attribute__((ext_vector_type(8))) short          bf16x8;
typedef __attribute__((ext_vector_type(4))) float          f32x4;
typedef __attribute__((ext_vector_type(8))) unsigned short u16x8;
typedef __attribute__((ext_vector_type(4))) unsigned short u16x4;

__device__ __forceinline__ unsigned short f2bf(float x) {
    unsigned u = __float_as_uint(x);
    u += 0x7fffu + ((u >> 16) & 1u);
    return (unsigned short)(u >> 16);
}
__device__ __forceinline__ float bf2f(unsigned short h) {
    return __uint_as_float((unsigned)h << 16);
}
__device__ __forceinline__ f32x4 mfma16(bf16x8 a, bf16x8 b, f32x4 c) {
    return __builtin_amdgcn_mfma_f32_16x16x32_bf16(a, b, c, 0, 0, 0);
}
__device__ __forceinline__ float fexp2(float x) {
    return __builtin_amdgcn_exp2f(x);
}
__device__ __forceinline__ float max3f(float a, float b, float c) {
    return fmaxf(fmaxf(a, b), c);   // clang fuses to v_max3_f32
}
// async global->LDS DMA, 16B/lane, dest = lds base + lane*16
__device__ __forceinline__ void dma16(const void* g, void* s) {
    __builtin_amdgcn_global_load_lds(
        (const __attribute__((address_space(1))) void*)g,
        (__attribute__((address_space(3))) void*)s, 16, 0, 0);
}

// ---------------------------------------------------------------------------
// Convert fp32 -> bf16 (round-to-nearest). ROUND-22: compact flat grid of
// 1480 blocks (1080 for X + 4x100 for weights) — the old (1080,5) grid had
// 3920 no-op blocks (weights need only 100 each).
// ---------------------------------------------------------------------------
__global__ __launch_bounds__(256) void split_kernel(
    const float* __restrict__ X,  const float* __restrict__ Wq,
    const float* __restrict__ Wk, const float* __restrict__ Wv,
    const float* __restrict__ Wo,
    unsigned short* __restrict__ Xh,  unsigned short* __restrict__ Wqh,
    unsigned short* __restrict__ Wkh, unsigned short* __restrict__ Wvh,
    unsigned short* __restrict__ Woh)
{
    const int b = blockIdx.x;
    const float* src; unsigned short* dh; int chunk; float s = 1.0f;
    if (b < 1080) {                       // X: 1080 * 4096 == M_TOT*DIM exactly
        src = X; dh = Xh; chunk = b;
    } else {
        const int wb = b - 1080;          // 0..399
        const int wsel = wb / 100;        // 0..3
        chunk = wb - wsel * 100;          // 0..99 (100*4096 == DIM*DIM)
        switch (wsel) {
            case 0:  src = Wq; dh = Wqh; s = SCALE * LOG2E; break;
            case 1:  src = Wk; dh = Wkh; break;
            case 2:  src = Wv; dh = Wvh; break;
            default: src = Wo; dh = Woh; break;
        }
    }
    const int base = chunk * 4096 + threadIdx.x * 16;
#pragma unroll
    for (int half = 0; half < 2; ++half) {
        const int bb = base + half * 8;
        float4 a4 = *(const float4*)(src + bb);
        float4 b4 = *(const float4*)(src + bb + 4);
        float vv[8] = {a4.x, a4.y, a4.z, a4.w, b4.x, b4.y, b4.z, b4.w};
        union { unsigned short u[8]; u16x8 v; } ph;
#pragma unroll
        for (int j = 0; j < 8; ++j) ph.u[j] = f2bf(vv[j] * s);
        *(u16x8*)(dh + bb) = ph.v;
    }
}

// ---------------------------------------------------------------------------
// QKV GEMM (single bf16). Tile 128(M) x 64(N), BK=32, block 256 (round-20:
// 1620 blocks = 6.3/CU; neutral vs 256-tile but kept — no regression).
// grid=(54,10,3); z epilogue: 0 -> Qh, 1 -> Kb, 2 -> Vt transpose.
// Bijective XCD swizzle (1620 = 8*202+4), m-major. 2-phase dbuf prefetch.
// ---------------------------------------------------------------------------
__global__ __launch_bounds__(256) void qkv_mfma_kernel(
    const unsigned short* __restrict__ Xh,
    const unsigned short* __restrict__ Wqh, const unsigned short* __restrict__ Wkh,
    const unsigned short* __restrict__ Wvh,
    unsigned short* __restrict__ Qh,
    unsigned short* __restrict__ Kb, unsigned short* __restrict__ VtG)
{
    __shared__ unsigned short smem[2][6144];    // 24 KB: A 128x32 + B 64x32 per buf

    // ---- XCD-aware bijective remap: 1620 blocks = 8*202 + 4 ----
    const int flat = blockIdx.x + 54 * (blockIdx.y + 10 * blockIdx.z);
    const int xcd  = flat & 7;
    const int slot = flat >> 3;                      // 0..202
    const int l    = (xcd < 4 ? xcd * 203 : 812 + (xcd - 4) * 202) + slot;
    const int m_idx = l / 30;                        // 0..53 (m-major: 30 tiles/panel)
    const int rem   = l - m_idx * 30;
    const int z     = rem / 10;                      // 0..2
    const int n_idx = rem - z * 10;                  // 0..9

    const unsigned short* WH = (z == 0) ? Wqh : ((z == 1) ? Wkh : Wvh);
    const int m0 = m_idx * 128;
    const int n0 = n_idx * 64;

    const int t    = threadIdx.x;
    const int w    = t >> 6;
    const int lane = t & 63;
    const int quad = lane >> 4;
    const int ln   = lane & 15;

    f32x4 acc[2][4];
#pragma unroll
    for (int mi = 0; mi < 2; ++mi)
#pragma unroll
        for (int nt = 0; nt < 4; ++nt)
#pragma unroll
            for (int e = 0; e < 4; ++e) acc[mi][nt][e] = 0.f;

    const int lr = lane >> 2;          // 0..15 (row within 16-row DMA chunk)
    const int lc = (lane & 3) * 8;     // 0,8,16,24 (shorts)

    // stage K-tile k0 into buffer buf (3 x 1KB DMA per wave)
    auto stage = [&](int buf, int k0) {
        unsigned short* As = smem[buf];            // 128*32
        unsigned short* Bs = smem[buf] + 4096;     // 64*32
        const unsigned short* gp = Xh + (size_t)(m0 + w * 32 + lr) * DIM + k0 + lc;
#pragma unroll
        for (int i = 0; i < 2; ++i)
            dma16(gp + (size_t)i * 16 * DIM, &As[(w * 32 + i * 16) * 32]);
        const size_t gb = (size_t)(n0 + w * 16 + lr) * DIM + k0 + lc;
        dma16(WH + gb, &Bs[w * 16 * 32]);
    };

    stage(0, 0);
    __syncthreads();                       // drains vmcnt(0): buf0 ready

    for (int k0 = 0; k0 < DIM; k0 += 32) {
        const int kb = (k0 >> 5) & 1;
        if (k0 + 32 < DIM) stage(kb ^ 1, k0 + 32);   // prefetch next tile

        const unsigned short* As = smem[kb];
        const unsigned short* Bs = smem[kb] + 4096;
        bf16x8 af[2];
#pragma unroll
        for (int mi = 0; mi < 2; ++mi)
            af[mi] = *(const bf16x8*)&As[(w * 32 + mi * 16 + ln) * 32 + quad * 8];
#pragma unroll
        for (int nt = 0; nt < 4; ++nt) {
            bf16x8 bh = *(const bf16x8*)&Bs[(nt * 16 + ln) * 32 + quad * 8];
#pragma unroll
            for (int mi = 0; mi < 2; ++mi)
                acc[mi][nt] = mfma16(af[mi], bh, acc[mi][nt]);
        }
        __syncthreads();   // vmcnt(0): prefetch landed; reads of kb done
    }

    if (z == 0) {
#pragma unroll
        for (int mi = 0; mi < 2; ++mi)
#pragma unroll
            for (int r = 0; r < 4; ++r) {
                const size_t row = m0 + w * 32 + mi * 16 + quad * 4 + r;
#pragma unroll
                for (int nt = 0; nt < 4; ++nt)
                    Qh[row * DIM + n0 + nt * 16 + ln] = f2bf(acc[mi][nt][r]);
            }
    } else if (z == 1) {
#pragma unroll
        for (int mi = 0; mi < 2; ++mi)
#pragma unroll
            for (int r = 0; r < 4; ++r) {
                const size_t row = m0 + w * 32 + mi * 16 + quad * 4 + r;
#pragma unroll
                for (int nt = 0; nt < 4; ++nt)
                    Kb[row * DIM + n0 + nt * 16 + ln] = f2bf(acc[mi][nt][r]);
            }
    } else {
        // transpose 128x64 -> Vt[64 n][128 m] via LDS (single pass, 4 waves)
        unsigned short* Vts = smem[0];   // 64 x 136 = 8704 shorts <= 12288 avail
        // last loop iteration ended with __syncthreads(): smem reads done
#pragma unroll
        for (int mi = 0; mi < 2; ++mi)
#pragma unroll
            for (int nt = 0; nt < 4; ++nt)
#pragma unroll
                for (int r = 0; r < 4; ++r)
                    Vts[(nt * 16 + ln) * 136 + w * 32 + mi * 16 + quad * 4 + r] =
                        f2bf(acc[mi][nt][r]);
        __syncthreads();
        const int nn = t & 63;
        const int c0 = (t >> 6) * 32;
#pragma unroll
        for (int i = 0; i < 4; ++i)
            *(u16x8*)(VtG + (size_t)(n0 + nn) * M_TOT + m0 + c0 + i * 8) =
                *(const u16x8*)&Vts[nn * 136 + c0 + i * 8];
    }
}

// ---------------------------------------------------------------------------
// Flash attention v16 (round-22) = v15 + FUSED MERGE. grid=(3,8,20), block
// 256 (4 waves x 48 q-rows). 2x18 cross split. Inner loop UNCHANGED from
// round-19 (P never touches LDS via sigma-permuted K staging; O^T PV;
// per-lane rescale/epilogue; defer-max; l inside PV MFMA via ones-row 80;
// zero bank conflicts; K dbuf DMA; V dbuf reg-stage).
// ROUND-22: merge_kernel eliminated. Each cross pair (fi,qt,h) shares an
// atomic counter (cnt, zeroed per launch via hipMemsetAsync). Both blocks
// write Pn/ml partials, __threadfence() (device scope — correctness does
// NOT depend on XCD placement), atomicAdd; the SECOND finisher re-reads
// both partials (L2-hot) and writes merged Oh rows directly. No spinning
// -> no deadlock possible.
// NOTE: never leave MFMA-read LDS uninitialized — 0*NaN = NaN.
// NOTE: no launch_bounds waves-cap / register-retained P across fences.
// z<16: cross chunk -> partials (Pn,ml) + fused merge; z>=16: self -> Oh.
// ---------------------------------------------------------------------------
__global__ __launch_bounds__(256, 2) void attn_mfma_kernel(
    const unsigned short* __restrict__ Qh,
    const unsigned short* __restrict__ Kb, const unsigned short* __restrict__ Vt,
    unsigned short* __restrict__ Oh,
    unsigned short* __restrict__ Pn, float2* __restrict__ ml,
    unsigned* __restrict__ cnt)
{
    // ---- XCD-aware remap: one head per XCD (480 = 8*60, bijective) ----
    const int flat = blockIdx.x + 3 * (blockIdx.y + 8 * blockIdx.z);
    const int h    = flat & 7;          // head = XCD
    const int slot = flat >> 3;         // 0..59
    const int z    = slot / 3;          // 0..19
    const int qt   = slot - z * 3;      // 0..2

    int f, kbase, nkt, idx = -1;
    if (z < 16) {
        idx = z;
        const int fi = z >> 1;
        f = 4 + fi;
        kbase = ((fi < 4 ? 4 : 8) + (z & 1) * 2) * SEQ;
        nkt = 18;
    } else {
        f = z - 16;
        kbase = f * SEQ;
        nkt = 9;
    }

    const int t    = threadIdx.x;
    const int w    = t >> 6;
    const int lane = t & 63;
    const int quad = lane >> 4;
    const int ln   = lane & 15;

    __shared__ unsigned short KhS[2][12 * 64 * 8]; // 24,576 B, sigma-permuted
    __shared__ unsigned short VtS[2][96 * 64];     // 24,576 B: 80 V rows + ones/zero group
    __shared__ int done_s;

    // sigma^-1: staging lane -> physical key offset within the 64-key tile
    const int klane = (lane & 3) | (((lane >> 4) & 1) << 2) |
                      (((lane >> 2) & 3) << 3) | (lane & 32);

    // staging helpers -------------------------------------------------------
    auto stage_k = [&](int buf, int kvt) {
        const unsigned short* kg = Kb + (size_t)(kbase + kvt * 64) * DIM + h * HD;
#pragma unroll
        for (int rnd = 0; rnd < 3; ++rnd) {
            const int g = rnd * 4 + w;          // d-colgroup 0..11
            dma16(kg + (size_t)klane * DIM + g * 8, &KhS[buf][g * 512]);
        }
    };
    u16x8 vreg[3];
    auto load_v = [&](int kvt) {
#pragma unroll
        for (int i = 0; i < 3; ++i) {
            const int u = t + i * 256;
            if (u < 640) {
                const int d = u >> 3, c8 = u & 7;
                vreg[i] = *(const u16x8*)(Vt + (size_t)(h * HD + d) * M_TOT +
                                          kbase + kvt * 64 + c8 * 8);
            }
        }
    };
    auto write_v = [&](int buf) {
#pragma unroll
        for (int i = 0; i < 3; ++i) {
            const int u = t + i * 256;
            if (u < 640) {
                const int d = u >> 3, c8 = u & 7;
                const int c8s = (c8 + 3 * d) & 7;
                *(u16x8*)&VtS[buf][d * 64 + c8s * 8] = vreg[i];
            }
        }
    };

    // ---- prologue part 1: issue tile-0 staging FIRST (latency in flight) ----
    stage_k(0, 0);
    load_v(0);

    // ---- ones/zero rows 80..95 of both V buffers (once) ----
    {
        const int buf = t >> 7;                  // 0..1
        const int c   = t & 127;                 // chunk within buffer
        const int row = 80 + (c >> 3);
        const unsigned short val = (row == 80) ? (unsigned short)0x3F80 : (unsigned short)0;
        union { unsigned short u[8]; u16x8 v; } fill;
#pragma unroll
        for (int j = 0; j < 8; ++j) fill.u[j] = val;
        *(u16x8*)&VtS[buf][row * 64 + (c & 7) * 8] = fill.v;
    }

    // ---- Q fragments (B-operand of S^T) — overlap with staging latency ----
    bf16x8 qf[3][3];
#pragma unroll
    for (int mi = 0; mi < 3; ++mi) {
        const int qrow = f * SEQ + qt * 192 + w * 48 + mi * 16 + ln;
        const unsigned short* qp = Qh + (size_t)qrow * DIM + h * HD;
#pragma unroll
        for (int kc = 0; kc < 3; ++kc) {
            const int dbase = kc * 32 + quad * 8;
            if (dbase < HD) {
                qf[mi][kc] = *(const bf16x8*)(qp + dbase);
            } else {
                union { unsigned short u[8]; bf16x8 v; } zz;
#pragma unroll
                for (int j = 0; j < 8; ++j) zz.u[j] = 0;
                qf[mi][kc] = zz.v;
            }
        }
    }

    // per-lane running max for q = mi*16 + ln (replicated across quads)
    float m_[3];
#pragma unroll
    for (int mi = 0; mi < 3; ++mi) m_[mi] = -INFINITY;

    // oacc is O^T: lane(ln,quad) reg r holds O[q=mi*16+ln][d=nt*16+quad*4+r];
    // nt=5 is the l-row group (meaningful value at quad==0, r==0).
    f32x4 oacc[3][6];
#pragma unroll
    for (int mi = 0; mi < 3; ++mi)
#pragma unroll
        for (int nt = 0; nt < 6; ++nt)
#pragma unroll
            for (int e = 0; e < 4; ++e) oacc[mi][nt][e] = 0.f;

    // ---- prologue part 2: land V, then barrier ----
    write_v(0);          // compiler waits vmcnt for vreg before ds_write
    __syncthreads();     // vmcnt(0): K-DMA landed; lgkm(0): V + fill visible

    for (int kt = 0; kt < nkt; ++kt) {
        const int cur = kt & 1;
        const bool pf = (kt + 1 < nkt);

        // ---- prefetch next tile: issue loads, keep in flight ----
        if (pf) {
            load_v(kt + 1);            // global->reg, vmcnt in flight
            stage_k(cur ^ 1, kt + 1);  // global->LDS DMA, vmcnt in flight
        }

        // ---- S^T = K.Q^T (zero-C first MFMA; sigma-permuted key rows) ----
        const f32x4 fz = {0.f, 0.f, 0.f, 0.f};
        f32x4 sacc[3][4];
#pragma unroll
        for (int nt = 0; nt < 4; ++nt) {
            const int ks = ln + 16 * (nt >> 1) + 32 * (nt & 1);
#pragma unroll
            for (int kc = 0; kc < 3; ++kc) {
                bf16x8 kf = *(const bf16x8*)&KhS[cur][((kc * 4 + quad) * 64 + ks) * 8];
#pragma unroll
                for (int mi = 0; mi < 3; ++mi)
                    sacc[mi][nt] = (kc == 0)
                        ? mfma16(kf, qf[mi][0], fz)
                        : mfma16(kf, qf[mi][kc], sacc[mi][nt]);  // swapped!
            }
        }

        // ---- softmax: max3 trees, defer-max (l handled by PV's l-row) ----
        float mxl[3];
#pragma unroll
        for (int mi = 0; mi < 3; ++mi) {
            const f32x4* S = sacc[mi];
            const float a = max3f(S[0][0], S[0][1], S[0][2]);
            const float b = max3f(S[0][3], S[1][0], S[1][1]);
            const float c = max3f(S[1][2], S[1][3], S[2][0]);
            const float d = max3f(S[2][1], S[2][2], S[2][3]);
            const float e = max3f(S[3][0], S[3][1], S[3][2]);
            mxl[mi] = fmaxf(max3f(a, b, c), max3f(d, e, S[3][3]));
        }
        const bool need = (mxl[0] > m_[0] + 8.0f) || (mxl[1] > m_[1] + 8.0f) ||
                          (mxl[2] > m_[2] + 8.0f);
        if (__any(need)) {           // wave-uniform slow path (rare)
#pragma unroll
            for (int mi = 0; mi < 3; ++mi) {
                float mx = fmaxf(mxl[mi], __shfl_xor(mxl[mi], 16));
                mx = fmaxf(mx, __shfl_xor(mx, 32));
                const float mnew = fmaxf(m_[mi], mx);
                const float aq = fexp2(m_[mi] - mnew);
                m_[mi] = mnew;
                // O^T layout: q = ln per-lane -> rescale needs NO shuffles;
                // nt=5 (l-row) rescaled too == old l_*=aq.
#pragma unroll
                for (int nt = 0; nt < 6; ++nt)
#pragma unroll
                    for (int e = 0; e < 4; ++e) oacc[mi][nt][e] *= aq;
            }
        }
        // ---- exp + pack straight into PV B-frags (NO LDS round-trip) ----
        bf16x8 pfv[3][2];
#pragma unroll
        for (int mi = 0; mi < 3; ++mi) {
            float p[4][4];
#pragma unroll
            for (int nt = 0; nt < 4; ++nt) {
#pragma unroll
                for (int r = 0; r < 4; ++r)
                    p[nt][r] = fexp2(sacc[mi][nt][r] - m_[mi]);
            }
            union { unsigned w[4]; bf16x8 v; } u0, u1;
            u0.w[0] = __builtin_amdgcn_perm(__float_as_uint(p[0][1]),
                                            __float_as_uint(p[0][0]), 0x07060302u);
            u0.w[1] = __builtin_amdgcn_perm(__float_as_uint(p[0][3]),
                                            __float_as_uint(p[0][2]), 0x07060302u);
            u0.w[2] = __builtin_amdgcn_perm(__float_as_uint(p[2][1]),
                                            __float_as_uint(p[2][0]), 0x07060302u);
            u0.w[3] = __builtin_amdgcn_perm(__float_as_uint(p[2][3]),
                                            __float_as_uint(p[2][2]), 0x07060302u);
            u1.w[0] = __builtin_amdgcn_perm(__float_as_uint(p[1][1]),
                                            __float_as_uint(p[1][0]), 0x07060302u);
            u1.w[1] = __builtin_amdgcn_perm(__float_as_uint(p[1][3]),
                                            __float_as_uint(p[1][2]), 0x07060302u);
            u1.w[2] = __builtin_amdgcn_perm(__float_as_uint(p[3][1]),
                                            __float_as_uint(p[3][0]), 0x07060302u);
            u1.w[3] = __builtin_amdgcn_perm(__float_as_uint(p[3][3]),
                                            __float_as_uint(p[3][2]), 0x07060302u);
            pfv[mi][0] = u0.v;
            pfv[mi][1] = u1.v;
        }

        // ---- O^T += V^T.P : A = V^T from VtS (incl. l-row nt=5), B = pfv ----
#pragma unroll
        for (int kc = 0; kc < 2; ++kc)
#pragma unroll
            for (int nt = 0; nt < 6; ++nt) {
                const int vrow = nt * 16 + ln;
                const int c8r  = ((kc * 4 + quad) + 3 * vrow) & 7;
                bf16x8 vf = *(const bf16x8*)&VtS[cur][vrow * 64 + c8r * 8];
#pragma unroll
                for (int mi = 0; mi < 3; ++mi)
                    oacc[mi][nt] = mfma16(vf, pfv[mi][kc], oacc[mi][nt]);
            }

        // ---- land prefetched V into the other buffer, then barrier ----
        if (pf) write_v(cur ^ 1);
        __syncthreads();   // vmcnt(0): next K-DMA landed; all reads of cur done
    }

    // ---- epilogue: l lives in oacc[mi][5][0] at quad==0 (lanes 0..15);
    //      broadcast to all quads with one shuffle per mi. ----
#pragma unroll
    for (int mi = 0; mi < 3; ++mi) {
        const float lsum = __shfl(oacc[mi][5][0], ln, 64);
        const float inv = 1.f / lsum;
        const int rr = qt * 192 + w * 48 + mi * 16 + ln;    // frame-local q-row
#pragma unroll
        for (int nt = 0; nt < 5; ++nt) {
            union { unsigned short u[4]; u16x4 v; } o4;
#pragma unroll
            for (int r = 0; r < 4; ++r) o4.u[r] = f2bf(oacc[mi][nt][r] * inv);
            const int dcol = h * HD + nt * 16 + quad * 4;
            if (idx < 0)
                *(u16x4*)&Oh[((size_t)f * SEQ + rr) * DIM + dcol] = o4.v;
            else
                *(u16x4*)&Pn[((size_t)idx * SEQ + rr) * DIM + dcol] = o4.v;
        }
    }
    if (idx >= 0 && lane < 16) {
#pragma unroll
        for (int mi = 0; mi < 3; ++mi) {
            const int rr = qt * 192 + w * 48 + mi * 16 + lane;
            ml[((size_t)idx * 8 + h) * SEQ + rr] =
                make_float2(m_[mi], oacc[mi][5][0]);   // lane<16 == quad 0
        }
    }

    // ---- fused merge: second finisher of each cross pair merges its
    //      192 rows x 80 cols (L2-hot) and writes Oh directly. ----
    if (idx >= 0) {
        __threadfence();            // release: Pn/ml visible device-wide
        __syncthreads();            // all waves' writes issued + fenced
        if (t == 0)
            done_s = (int)atomicAdd(&cnt[(z >> 1) * 24 + qt * 8 + h], 1u);
        __syncthreads();
        if (done_s == 1) {
            __threadfence();        // acquire: see sibling's Pn/ml
            const int fi = z >> 1;
            const int i0 = fi * 2, i1 = i0 + 1;
#pragma unroll
            for (int i = 0; i < 15; ++i) {       // 192*20 u16x4 units / 256
                const int u   = t + i * 256;
                const int row = u / 20;          // 0..191
                const int ch  = u - row * 20;    // 0..19
                const int rr  = qt * 192 + row;
                const int col = h * HD + ch * 4;
                const float2 a = ml[((size_t)i0 * 8 + h) * SEQ + rr];
                const float2 b = ml[((size_t)i1 * 8 + h) * SEQ + rr];
                const float M  = fmaxf(a.x, b.x);
                const float w0 = fexp2(a.x - M) * a.y;
                const float w1 = fexp2(b.x - M) * b.y;
                const float inv = 1.f / (w0 + w1);
                u16x4 q0 = *(const u16x4*)&Pn[((size_t)i0 * SEQ + rr) * DIM + col];
                u16x4 q1 = *(const u16x4*)&Pn[((size_t)i1 * SEQ + rr) * DIM + col];
                union { unsigned short us[4]; u16x4 v; } o;
#pragma unroll
                for (int j = 0; j < 4; ++j)
                    o.us[j] = f2bf((w0 * bf2f(q0[j]) + w1 * bf2f(q1[j])) * inv);
                *(u16x4*)&Oh[((size_t)(4 + fi) * SEQ + rr) * DIM + col] = o.v;
            }
        }
    }
}

// ---------------------------------------------------------------------------
// Output projection: out = Oh * Wo^T + bo (single bf16), fp32 out.
// Tile 128x64, grid (54,10) = 540 blocks = 2.1/CU. BK=32, global_load_lds
// staging, 2-phase dbuf prefetch, bijective XCD swizzle (540 = 8*67 + 4).
// ---------------------------------------------------------------------------
__global__ __launch_bounds__(256) void oproj_mfma_kernel(
    const unsigned short* __restrict__ Oh,
    const unsigned short* __restrict__ Woh,
    const float* __restrict__ bo, float* __restrict__ out)
{
    __shared__ unsigned short smem[2][6144];    // 24 KB

    // ---- XCD-aware bijective remap: 540 blocks = 8*67 + 4 ----
    const int flat = blockIdx.x + 54 * blockIdx.y;
    const int xcd  = flat & 7;
    const int slot = flat >> 3;
    const int l    = (xcd < 4 ? xcd * 68 : 272 + (xcd - 4) * 67) + slot;
    const int m_idx = l / 10;                        // 0..53 (m-major)
    const int n_idx = l - m_idx * 10;
    const int m0 = m_idx * 128;
    const int n0 = n_idx * 64;

    const int t    = threadIdx.x;
    const int w    = t >> 6;
    const int lane = t & 63;
    const int quad = lane >> 4;
    const int ln   = lane & 15;

    f32x4 acc[2][4];
#pragma unroll
    for (int mi = 0; mi < 2; ++mi)
#pragma unroll
        for (int nt = 0; nt < 4; ++nt)
#pragma unroll
            for (int e = 0; e < 4; ++e) acc[mi][nt][e] = 0.f;

    const int lr = lane >> 2;
    const int lc = (lane & 3) * 8;

    auto stage = [&](int buf, int k0) {
        unsigned short* As = smem[buf];            // 128*32
        unsigned short* Bs = smem[buf] + 4096;     // 64*32
        const unsigned short* gp = Oh + (size_t)(m0 + w * 32 + lr) * DIM + k0 + lc;
#pragma unroll
        for (int i = 0; i < 2; ++i)
            dma16(gp + (size_t)i * 16 * DIM, &As[(w * 32 + i * 16) * 32]);
        const size_t gb = (size_t)(n0 + w * 16 + lr) * DIM + k0 + lc;
        dma16(Woh + gb, &Bs[w * 16 * 32]);
    };

    stage(0, 0);
    __syncthreads();

    for (int k0 = 0; k0 < DIM; k0 += 32) {
        const int kb = (k0 >> 5) & 1;
        if (k0 + 32 < DIM) stage(kb ^ 1, k0 + 32);

        const unsigned short* As = smem[kb];
        const unsigned short* Bs = smem[kb] + 4096;
        bf16x8 af[2];
#pragma unroll
        for (int mi = 0; mi < 2; ++mi)
            af[mi] = *(const bf16x8*)&As[(w * 32 + mi * 16 + ln) * 32 + quad * 8];
#pragma unroll
        for (int nt = 0; nt < 4; ++nt) {
            bf16x8 bh = *(const bf16x8*)&Bs[(nt * 16 + ln) * 32 + quad * 8];
#pragma unroll
            for (int mi = 0; mi < 2; ++mi)
                acc[mi][nt] = mfma16(af[mi], bh, acc[mi][nt]);
        }
        __syncthreads();
    }

#pragma unroll
    for (int mi = 0; mi < 2; ++mi)
#pragma unroll
        for (int r = 0; r < 4; ++r) {
            const size_t row = m0 + w * 32 + mi * 16 + quad * 4 + r;
#pragma unroll
            for (int nt = 0; nt < 4; ++nt) {
                const int col = n0 + nt * 16 + ln;
                out[row * DIM + col] = acc[mi][nt][r] + bo[col];
            }
        }
}

// ---------------------------------------------------------------------------
extern "C" void kernel_launch(void* const* d_in, const int* in_sizes, int n_in,
                              void* d_out, int out_size, void* d_ws, size_t ws_size,
                              hipStream_t stream)
{
    const float* x  = (const float*)d_in[0];
    const float* Wq = (const float*)d_in[1];
    const float* Wk = (const float*)d_in[2];
    const float* Wv = (const float*)d_in[3];
    const float* Wo = (const float*)d_in[4];
    const float* bo = (const float*)d_in[5];
    float* out = (float*)d_out;

    const size_t NX = (size_t)M_TOT * DIM;   // 4,423,680
    const size_t NW = (size_t)DIM * DIM;     // 409,600
    unsigned short* p = (unsigned short*)d_ws;
    unsigned short* Wqh = p;  p += NW;
    unsigned short* Wkh = p;  p += NW;
    unsigned short* Wvh = p;  p += NW;
    unsigned short* Woh = p;  p += NW;
    unsigned short* Xh  = p;  p += NX;
    unsigned short* Qhb = p;  p += NX;
    unsigned short* Kbb = p;  p += NX;
    unsigned short* Vtb = p;  p += NX;
    unsigned short* Ohb = Xh;                 // Xh dead after QKV GEMM
    unsigned* cnt = (unsigned*)p;             // 192 pair counters (768 B)

    // flash-decoding partials live in d_out (dead until oproj rewrites it)
    unsigned short* Pn = (unsigned short*)d_out;            // 16*576*640 bf16
    float2* ml = (float2*)((char*)d_out + (size_t)16 * SEQ * DIM * 2);

    hipMemsetAsync(cnt, 0, 192 * sizeof(unsigned), stream);

    split_kernel<<<dim3(1480), 256, 0, stream>>>(x, Wq, Wk, Wv, Wo,
        Xh, Wqh, Wkh, Wvh, Woh);

    dim3 g1(M_TOT / 128, DIM / 64, 3);
    qkv_mfma_kernel<<<g1, 256, 0, stream>>>(Xh, Wqh, Wkh, Wvh, Qhb, Kbb, Vtb);

    dim3 g2(3, HEADS, 20);
    attn_mfma_kernel<<<g2, 256, 0, stream>>>(Qhb, Kbb, Vtb, Ohb, Pn, ml, cnt);

    dim3 g4(M_TOT / 128, DIM / 64);
    oproj_mfma_kernel<<<g4, 256, 0, stream>>>(Ohb, Woh, bo, out);
}

// Round 13
// 184.788 us; speedup vs baseline: 1.4172x; 1.4172x over previous
//
#include <hip/hip_runtime.h>
#include <hip/hip_bf16.h>

#define SEQ    576
#define DIM    640
#define HEADS  8
#define HD     80          // DIM / HEADS
#define NF     4
#define NB     12          // 3 * NF
#define M_TOT  (NB * SEQ)  // 6912
#define SCALE  0.11180339887498949f   // 1/sqrt(80)
#define LOG2E  1.4426950408889634f

typedef __attribute__((ext_vector_type(8))) short          bf16x8;
typedef __attribute__((ext_vector_type(4))) float          f32x4;
typedef __attribute__((ext_vector_type(8))) unsigned short u16x8;
typedef __attribute__((ext_vector_type(4))) unsigned short u16x4;

__device__ __forceinline__ unsigned short f2bf(float x) {
    unsigned u = __float_as_uint(x);
    u += 0x7fffu + ((u >> 16) & 1u);
    return (unsigned short)(u >> 16);
}
__device__ __forceinline__ float bf2f(unsigned short h) {
    return __uint_as_float((unsigned)h << 16);
}
__device__ __forceinline__ f32x4 mfma16(bf16x8 a, bf16x8 b, f32x4 c) {
    return __builtin_amdgcn_mfma_f32_16x16x32_bf16(a, b, c, 0, 0, 0);
}
__device__ __forceinline__ float fexp2(float x) {
    return __builtin_amdgcn_exp2f(x);
}
__device__ __forceinline__ float max3f(float a, float b, float c) {
    return fmaxf(fmaxf(a, b), c);   // clang fuses to v_max3_f32
}
// async global->LDS DMA, 16B/lane, dest = lds base + lane*16
__device__ __forceinline__ void dma16(const void* g, void* s) {
    __builtin_amdgcn_global_load_lds(
        (const __attribute__((address_space(1))) void*)g,
        (__attribute__((address_space(3))) void*)s, 16, 0, 0);
}

// ---------------------------------------------------------------------------
// Convert fp32 -> bf16 (round-to-nearest). Compact flat grid of 1480 blocks
// (1080 for X + 4x100 for weights) — no no-op blocks (round-22 keeper).
// ---------------------------------------------------------------------------
__global__ __launch_bounds__(256) void split_kernel(
    const float* __restrict__ X,  const float* __restrict__ Wq,
    const float* __restrict__ Wk, const float* __restrict__ Wv,
    const float* __restrict__ Wo,
    unsigned short* __restrict__ Xh,  unsigned short* __restrict__ Wqh,
    unsigned short* __restrict__ Wkh, unsigned short* __restrict__ Wvh,
    unsigned short* __restrict__ Woh)
{
    const int b = blockIdx.x;
    const float* src; unsigned short* dh; int chunk; float s = 1.0f;
    if (b < 1080) {                       // X: 1080 * 4096 == M_TOT*DIM exactly
        src = X; dh = Xh; chunk = b;
    } else {
        const int wb = b - 1080;          // 0..399
        const int wsel = wb / 100;        // 0..3
        chunk = wb - wsel * 100;          // 0..99 (100*4096 == DIM*DIM)
        switch (wsel) {
            case 0:  src = Wq; dh = Wqh; s = SCALE * LOG2E; break;
            case 1:  src = Wk; dh = Wkh; break;
            case 2:  src = Wv; dh = Wvh; break;
            default: src = Wo; dh = Woh; break;
        }
    }
    const int base = chunk * 4096 + threadIdx.x * 16;
#pragma unroll
    for (int half = 0; half < 2; ++half) {
        const int bb = base + half * 8;
        float4 a4 = *(const float4*)(src + bb);
        float4 b4 = *(const float4*)(src + bb + 4);
        float vv[8] = {a4.x, a4.y, a4.z, a4.w, b4.x, b4.y, b4.z, b4.w};
        union { unsigned short u[8]; u16x8 v; } ph;
#pragma unroll
        for (int j = 0; j < 8; ++j) ph.u[j] = f2bf(vv[j] * s);
        *(u16x8*)(dh + bb) = ph.v;
    }
}

// ---------------------------------------------------------------------------
// QKV GEMM (single bf16). Tile 128(M) x 64(N), BK=32, block 256.
// grid=(54,10,3); z epilogue: 0 -> Qh, 1 -> Kb, 2 -> Vt transpose.
// Bijective XCD swizzle (1620 = 8*202+4), m-major. 2-phase dbuf prefetch.
// ---------------------------------------------------------------------------
__global__ __launch_bounds__(256) void qkv_mfma_kernel(
    const unsigned short* __restrict__ Xh,
    const unsigned short* __restrict__ Wqh, const unsigned short* __restrict__ Wkh,
    const unsigned short* __restrict__ Wvh,
    unsigned short* __restrict__ Qh,
    unsigned short* __restrict__ Kb, unsigned short* __restrict__ VtG)
{
    __shared__ unsigned short smem[2][6144];    // 24 KB: A 128x32 + B 64x32 per buf

    // ---- XCD-aware bijective remap: 1620 blocks = 8*202 + 4 ----
    const int flat = blockIdx.x + 54 * (blockIdx.y + 10 * blockIdx.z);
    const int xcd  = flat & 7;
    const int slot = flat >> 3;                      // 0..202
    const int l    = (xcd < 4 ? xcd * 203 : 812 + (xcd - 4) * 202) + slot;
    const int m_idx = l / 30;                        // 0..53 (m-major: 30 tiles/panel)
    const int rem   = l - m_idx * 30;
    const int z     = rem / 10;                      // 0..2
    const int n_idx = rem - z * 10;                  // 0..9

    const unsigned short* WH = (z == 0) ? Wqh : ((z == 1) ? Wkh : Wvh);
    const int m0 = m_idx * 128;
    const int n0 = n_idx * 64;

    const int t    = threadIdx.x;
    const int w    = t >> 6;
    const int lane = t & 63;
    const int quad = lane >> 4;
    const int ln   = lane & 15;

    f32x4 acc[2][4];
#pragma unroll
    for (int mi = 0; mi < 2; ++mi)
#pragma unroll
        for (int nt = 0; nt < 4; ++nt)
#pragma unroll
            for (int e = 0; e < 4; ++e) acc[mi][nt][e] = 0.f;

    const int lr = lane >> 2;          // 0..15 (row within 16-row DMA chunk)
    const int lc = (lane & 3) * 8;     // 0,8,16,24 (shorts)

    // stage K-tile k0 into buffer buf (3 x 1KB DMA per wave)
    auto stage = [&](int buf, int k0) {
        unsigned short* As = smem[buf];            // 128*32
        unsigned short* Bs = smem[buf] + 4096;     // 64*32
        const unsigned short* gp = Xh + (size_t)(m0 + w * 32 + lr) * DIM + k0 + lc;
#pragma unroll
        for (int i = 0; i < 2; ++i)
            dma16(gp + (size_t)i * 16 * DIM, &As[(w * 32 + i * 16) * 32]);
        const size_t gb = (size_t)(n0 + w * 16 + lr) * DIM + k0 + lc;
        dma16(WH + gb, &Bs[w * 16 * 32]);
    };

    stage(0, 0);
    __syncthreads();                       // drains vmcnt(0): buf0 ready

    for (int k0 = 0; k0 < DIM; k0 += 32) {
        const int kb = (k0 >> 5) & 1;
        if (k0 + 32 < DIM) stage(kb ^ 1, k0 + 32);   // prefetch next tile

        const unsigned short* As = smem[kb];
        const unsigned short* Bs = smem[kb] + 4096;
        bf16x8 af[2];
#pragma unroll
        for (int mi = 0; mi < 2; ++mi)
            af[mi] = *(const bf16x8*)&As[(w * 32 + mi * 16 + ln) * 32 + quad * 8];
#pragma unroll
        for (int nt = 0; nt < 4; ++nt) {
            bf16x8 bh = *(const bf16x8*)&Bs[(nt * 16 + ln) * 32 + quad * 8];
#pragma unroll
            for (int mi = 0; mi < 2; ++mi)
                acc[mi][nt] = mfma16(af[mi], bh, acc[mi][nt]);
        }
        __syncthreads();   // vmcnt(0): prefetch landed; reads of kb done
    }

    if (z == 0) {
#pragma unroll
        for (int mi = 0; mi < 2; ++mi)
#pragma unroll
            for (int r = 0; r < 4; ++r) {
                const size_t row = m0 + w * 32 + mi * 16 + quad * 4 + r;
#pragma unroll
                for (int nt = 0; nt < 4; ++nt)
                    Qh[row * DIM + n0 + nt * 16 + ln] = f2bf(acc[mi][nt][r]);
            }
    } else if (z == 1) {
#pragma unroll
        for (int mi = 0; mi < 2; ++mi)
#pragma unroll
            for (int r = 0; r < 4; ++r) {
                const size_t row = m0 + w * 32 + mi * 16 + quad * 4 + r;
#pragma unroll
                for (int nt = 0; nt < 4; ++nt)
                    Kb[row * DIM + n0 + nt * 16 + ln] = f2bf(acc[mi][nt][r]);
            }
    } else {
        // transpose 128x64 -> Vt[64 n][128 m] via LDS (single pass, 4 waves)
        unsigned short* Vts = smem[0];   // 64 x 136 = 8704 shorts <= 12288 avail
        // last loop iteration ended with __syncthreads(): smem reads done
#pragma unroll
        for (int mi = 0; mi < 2; ++mi)
#pragma unroll
            for (int nt = 0; nt < 4; ++nt)
#pragma unroll
                for (int r = 0; r < 4; ++r)
                    Vts[(nt * 16 + ln) * 136 + w * 32 + mi * 16 + quad * 4 + r] =
                        f2bf(acc[mi][nt][r]);
        __syncthreads();
        const int nn = t & 63;
        const int c0 = (t >> 6) * 32;
#pragma unroll
        for (int i = 0; i < 4; ++i)
            *(u16x8*)(VtG + (size_t)(n0 + nn) * M_TOT + m0 + c0 + i * 8) =
                *(const u16x8*)&Vts[nn * 136 + c0 + i * 8];
    }
}

// ---------------------------------------------------------------------------
// Flash attention v15 (round-19 structure, REVERTED from round-22's fused
// merge: __threadfence() device-scope release on gfx950 forces L2
// writeback/invalidate (per-XCD L2s non-coherent) — it destroyed the
// kernel's L2-resident K/V locality (FETCH 19->29 MB, MfmaUtil 25->11%,
// attn 54->136 us). NEVER put device-scope fences inside an L2-locality-
// critical kernel; the separate merge kernel (~3 us) is cheap insurance.
// grid=(3,8,20), block 256 (4 waves x 48 q-rows). 2x18 cross split.
// Inner loop: P never touches LDS (sigma-permuted K staging); O^T PV;
// per-lane rescale/epilogue; defer-max; zero bank conflicts; K dbuf via
// DMA; V dbuf via reg-stage; l computed INSIDE PV MFMA via ones-row 80.
// NOTE: never leave MFMA-read LDS uninitialized — 0*NaN = NaN.
// NOTE: no launch_bounds waves-cap / register-retained P across fences.
// z<16: cross chunk -> partials (Pn,ml); z>=16: self frame -> Oh.
// ---------------------------------------------------------------------------
__global__ __launch_bounds__(256, 2) void attn_mfma_kernel(
    const unsigned short* __restrict__ Qh,
    const unsigned short* __restrict__ Kb, const unsigned short* __restrict__ Vt,
    unsigned short* __restrict__ Oh,
    unsigned short* __restrict__ Pn, float2* __restrict__ ml)
{
    // ---- XCD-aware remap: one head per XCD (480 = 8*60, bijective) ----
    const int flat = blockIdx.x + 3 * (blockIdx.y + 8 * blockIdx.z);
    const int h    = flat & 7;          // head = XCD
    const int slot = flat >> 3;         // 0..59
    const int z    = slot / 3;          // 0..19
    const int qt   = slot - z * 3;      // 0..2

    int f, kbase, nkt, idx = -1;
    if (z < 16) {
        idx = z;
        const int fi = z >> 1;
        f = 4 + fi;
        kbase = ((fi < 4 ? 4 : 8) + (z & 1) * 2) * SEQ;
        nkt = 18;
    } else {
        f = z - 16;
        kbase = f * SEQ;
        nkt = 9;
    }

    const int t    = threadIdx.x;
    const int w    = t >> 6;
    const int lane = t & 63;
    const int quad = lane >> 4;
    const int ln   = lane & 15;

    __shared__ unsigned short KhS[2][12 * 64 * 8]; // 24,576 B, sigma-permuted
    __shared__ unsigned short VtS[2][96 * 64];     // 24,576 B: 80 V rows + ones/zero group

    // sigma^-1: staging lane -> physical key offset within the 64-key tile
    const int klane = (lane & 3) | (((lane >> 4) & 1) << 2) |
                      (((lane >> 2) & 3) << 3) | (lane & 32);

    // staging helpers -------------------------------------------------------
    auto stage_k = [&](int buf, int kvt) {
        const unsigned short* kg = Kb + (size_t)(kbase + kvt * 64) * DIM + h * HD;
#pragma unroll
        for (int rnd = 0; rnd < 3; ++rnd) {
            const int g = rnd * 4 + w;          // d-colgroup 0..11
            dma16(kg + (size_t)klane * DIM + g * 8, &KhS[buf][g * 512]);
        }
    };
    u16x8 vreg[3];
    auto load_v = [&](int kvt) {
#pragma unroll
        for (int i = 0; i < 3; ++i) {
            const int u = t + i * 256;
            if (u < 640) {
                const int d = u >> 3, c8 = u & 7;
                vreg[i] = *(const u16x8*)(Vt + (size_t)(h * HD + d) * M_TOT +
                                          kbase + kvt * 64 + c8 * 8);
            }
        }
    };
    auto write_v = [&](int buf) {
#pragma unroll
        for (int i = 0; i < 3; ++i) {
            const int u = t + i * 256;
            if (u < 640) {
                const int d = u >> 3, c8 = u & 7;
                const int c8s = (c8 + 3 * d) & 7;
                *(u16x8*)&VtS[buf][d * 64 + c8s * 8] = vreg[i];
            }
        }
    };

    // ---- prologue part 1: issue tile-0 staging FIRST (latency in flight) ----
    stage_k(0, 0);
    load_v(0);

    // ---- ones/zero rows 80..95 of both V buffers (once) ----
    {
        const int buf = t >> 7;                  // 0..1
        const int c   = t & 127;                 // chunk within buffer
        const int row = 80 + (c >> 3);
        const unsigned short val = (row == 80) ? (unsigned short)0x3F80 : (unsigned short)0;
        union { unsigned short u[8]; u16x8 v; } fill;
#pragma unroll
        for (int j = 0; j < 8; ++j) fill.u[j] = val;
        *(u16x8*)&VtS[buf][row * 64 + (c & 7) * 8] = fill.v;
    }

    // ---- Q fragments (B-operand of S^T) — overlap with staging latency ----
    bf16x8 qf[3][3];
#pragma unroll
    for (int mi = 0; mi < 3; ++mi) {
        const int qrow = f * SEQ + qt * 192 + w * 48 + mi * 16 + ln;
        const unsigned short* qp = Qh + (size_t)qrow * DIM + h * HD;
#pragma unroll
        for (int kc = 0; kc < 3; ++kc) {
            const int dbase = kc * 32 + quad * 8;
            if (dbase < HD) {
                qf[mi][kc] = *(const bf16x8*)(qp + dbase);
            } else {
                union { unsigned short u[8]; bf16x8 v; } zz;
#pragma unroll
                for (int j = 0; j < 8; ++j) zz.u[j] = 0;
                qf[mi][kc] = zz.v;
            }
        }
    }

    // per-lane running max for q = mi*16 + ln (replicated across quads)
    float m_[3];
#pragma unroll
    for (int mi = 0; mi < 3; ++mi) m_[mi] = -INFINITY;

    // oacc is O^T: lane(ln,quad) reg r holds O[q=mi*16+ln][d=nt*16+quad*4+r];
    // nt=5 is the l-row group (meaningful value at quad==0, r==0).
    f32x4 oacc[3][6];
#pragma unroll
    for (int mi = 0; mi < 3; ++mi)
#pragma unroll
        for (int nt = 0; nt < 6; ++nt)
#pragma unroll
            for (int e = 0; e < 4; ++e) oacc[mi][nt][e] = 0.f;

    // ---- prologue part 2: land V, then barrier ----
    write_v(0);          // compiler waits vmcnt for vreg before ds_write
    __syncthreads();     // vmcnt(0): K-DMA landed; lgkm(0): V + fill visible

    for (int kt = 0; kt < nkt; ++kt) {
        const int cur = kt & 1;
        const bool pf = (kt + 1 < nkt);

        // ---- prefetch next tile: issue loads, keep in flight ----
        if (pf) {
            load_v(kt + 1);            // global->reg, vmcnt in flight
            stage_k(cur ^ 1, kt + 1);  // global->LDS DMA, vmcnt in flight
        }

        // ---- S^T = K.Q^T (zero-C first MFMA; sigma-permuted key rows) ----
        const f32x4 fz = {0.f, 0.f, 0.f, 0.f};
        f32x4 sacc[3][4];
#pragma unroll
        for (int nt = 0; nt < 4; ++nt) {
            const int ks = ln + 16 * (nt >> 1) + 32 * (nt & 1);
#pragma unroll
            for (int kc = 0; kc < 3; ++kc) {
                bf16x8 kf = *(const bf16x8*)&KhS[cur][((kc * 4 + quad) * 64 + ks) * 8];
#pragma unroll
                for (int mi = 0; mi < 3; ++mi)
                    sacc[mi][nt] = (kc == 0)
                        ? mfma16(kf, qf[mi][0], fz)
                        : mfma16(kf, qf[mi][kc], sacc[mi][nt]);  // swapped!
            }
        }

        // ---- softmax: max3 trees, defer-max (l handled by PV's l-row) ----
        float mxl[3];
#pragma unroll
        for (int mi = 0; mi < 3; ++mi) {
            const f32x4* S = sacc[mi];
            const float a = max3f(S[0][0], S[0][1], S[0][2]);
            const float b = max3f(S[0][3], S[1][0], S[1][1]);
            const float c = max3f(S[1][2], S[1][3], S[2][0]);
            const float d = max3f(S[2][1], S[2][2], S[2][3]);
            const float e = max3f(S[3][0], S[3][1], S[3][2]);
            mxl[mi] = fmaxf(max3f(a, b, c), max3f(d, e, S[3][3]));
        }
        const bool need = (mxl[0] > m_[0] + 8.0f) || (mxl[1] > m_[1] + 8.0f) ||
                          (mxl[2] > m_[2] + 8.0f);
        if (__any(need)) {           // wave-uniform slow path (rare)
#pragma unroll
            for (int mi = 0; mi < 3; ++mi) {
                float mx = fmaxf(mxl[mi], __shfl_xor(mxl[mi], 16));
                mx = fmaxf(mx, __shfl_xor(mx, 32));
                const float mnew = fmaxf(m_[mi], mx);
                const float aq = fexp2(m_[mi] - mnew);
                m_[mi] = mnew;
                // O^T layout: q = ln per-lane -> rescale needs NO shuffles;
                // nt=5 (l-row) rescaled too == old l_*=aq.
#pragma unroll
                for (int nt = 0; nt < 6; ++nt)
#pragma unroll
                    for (int e = 0; e < 4; ++e) oacc[mi][nt][e] *= aq;
            }
        }
        // ---- exp + pack straight into PV B-frags (NO LDS round-trip) ----
        bf16x8 pfv[3][2];
#pragma unroll
        for (int mi = 0; mi < 3; ++mi) {
            float p[4][4];
#pragma unroll
            for (int nt = 0; nt < 4; ++nt) {
#pragma unroll
                for (int r = 0; r < 4; ++r)
                    p[nt][r] = fexp2(sacc[mi][nt][r] - m_[mi]);
            }
            union { unsigned w[4]; bf16x8 v; } u0, u1;
            u0.w[0] = __builtin_amdgcn_perm(__float_as_uint(p[0][1]),
                                            __float_as_uint(p[0][0]), 0x07060302u);
            u0.w[1] = __builtin_amdgcn_perm(__float_as_uint(p[0][3]),
                                            __float_as_uint(p[0][2]), 0x07060302u);
            u0.w[2] = __builtin_amdgcn_perm(__float_as_uint(p[2][1]),
                                            __float_as_uint(p[2][0]), 0x07060302u);
            u0.w[3] = __builtin_amdgcn_perm(__float_as_uint(p[2][3]),
                                            __float_as_uint(p[2][2]), 0x07060302u);
            u1.w[0] = __builtin_amdgcn_perm(__float_as_uint(p[1][1]),
                                            __float_as_uint(p[1][0]), 0x07060302u);
            u1.w[1] = __builtin_amdgcn_perm(__float_as_uint(p[1][3]),
                                            __float_as_uint(p[1][2]), 0x07060302u);
            u1.w[2] = __builtin_amdgcn_perm(__float_as_uint(p[3][1]),
                                            __float_as_uint(p[3][0]), 0x07060302u);
            u1.w[3] = __builtin_amdgcn_perm(__float_as_uint(p[3][3]),
                                            __float_as_uint(p[3][2]), 0x07060302u);
            pfv[mi][0] = u0.v;
            pfv[mi][1] = u1.v;
        }

        // ---- O^T += V^T.P : A = V^T from VtS (incl. l-row nt=5), B = pfv ----
#pragma unroll
        for (int kc = 0; kc < 2; ++kc)
#pragma unroll
            for (int nt = 0; nt < 6; ++nt) {
                const int vrow = nt * 16 + ln;
                const int c8r  = ((kc * 4 + quad) + 3 * vrow) & 7;
                bf16x8 vf = *(const bf16x8*)&VtS[cur][vrow * 64 + c8r * 8];
#pragma unroll
                for (int mi = 0; mi < 3; ++mi)
                    oacc[mi][nt] = mfma16(vf, pfv[mi][kc], oacc[mi][nt]);
            }

        // ---- land prefetched V into the other buffer, then barrier ----
        if (pf) write_v(cur ^ 1);
        __syncthreads();   // vmcnt(0): next K-DMA landed; all reads of cur done
    }

    // ---- epilogue: l lives in oacc[mi][5][0] at quad==0 (lanes 0..15);
    //      broadcast to all quads with one shuffle per mi. ----
#pragma unroll
    for (int mi = 0; mi < 3; ++mi) {
        const float lsum = __shfl(oacc[mi][5][0], ln, 64);
        const float inv = 1.f / lsum;
        const int rr = qt * 192 + w * 48 + mi * 16 + ln;    // frame-local q-row
#pragma unroll
        for (int nt = 0; nt < 5; ++nt) {
            union { unsigned short u[4]; u16x4 v; } o4;
#pragma unroll
            for (int r = 0; r < 4; ++r) o4.u[r] = f2bf(oacc[mi][nt][r] * inv);
            const int dcol = h * HD + nt * 16 + quad * 4;
            if (idx < 0)
                *(u16x4*)&Oh[((size_t)f * SEQ + rr) * DIM + dcol] = o4.v;
            else
                *(u16x4*)&Pn[((size_t)idx * SEQ + rr) * DIM + dcol] = o4.v;
        }
    }
    if (idx >= 0 && lane < 16) {
#pragma unroll
        for (int mi = 0; mi < 3; ++mi) {
            const int rr = qt * 192 + w * 48 + mi * 16 + lane;
            ml[((size_t)idx * 8 + h) * SEQ + rr] =
                make_float2(m_[mi], oacc[mi][5][0]);   // lane<16 == quad 0
        }
    }
}

// ---------------------------------------------------------------------------
// Merge the two partials of each cross frame. grid=(576,8), block 320.
// ---------------------------------------------------------------------------
__global__ __launch_bounds__(320) void merge_kernel(
    const unsigned short* __restrict__ Pn, const float2* __restrict__ ml,
    unsigned short* __restrict__ Oh)
{
    const int row = blockIdx.x;   // 0..575
    const int fi  = blockIdx.y;   // 0..7
    const int t   = threadIdx.x;  // 0..319
    const int i0  = fi * 2, i1 = i0 + 1;
#pragma unroll
    for (int rep = 0; rep < 2; ++rep) {
        const int col = t + rep * 320;
        const int h = col / 80;
        const float2 a = ml[((size_t)i0 * 8 + h) * SEQ + row];
        const float2 b = ml[((size_t)i1 * 8 + h) * SEQ + row];
        const float M  = fmaxf(a.x, b.x);
        const float w0 = fexp2(a.x - M) * a.y;
        const float w1 = fexp2(b.x - M) * b.y;
        const float inv = 1.f / (w0 + w1);
        const float p0 = bf2f(Pn[((size_t)i0 * SEQ + row) * DIM + col]);
        const float p1 = bf2f(Pn[((size_t)i1 * SEQ + row) * DIM + col]);
        Oh[((size_t)(4 + fi) * SEQ + row) * DIM + col] = f2bf((w0 * p0 + w1 * p1) * inv);
    }
}

// ---------------------------------------------------------------------------
// Output projection: out = Oh * Wo^T + bo (single bf16), fp32 out.
// Tile 128x64, grid (54,10) = 540 blocks = 2.1/CU. BK=32, global_load_lds
// staging, 2-phase dbuf prefetch, bijective XCD swizzle (540 = 8*67 + 4).
// ---------------------------------------------------------------------------
__global__ __launch_bounds__(256) void oproj_mfma_kernel(
    const unsigned short* __restrict__ Oh,
    const unsigned short* __restrict__ Woh,
    const float* __restrict__ bo, float* __restrict__ out)
{
    __shared__ unsigned short smem[2][6144];    // 24 KB

    // ---- XCD-aware bijective remap: 540 blocks = 8*67 + 4 ----
    const int flat = blockIdx.x + 54 * blockIdx.y;
    const int xcd  = flat & 7;
    const int slot = flat >> 3;
    const int l    = (xcd < 4 ? xcd * 68 : 272 + (xcd - 4) * 67) + slot;
    const int m_idx = l / 10;                        // 0..53 (m-major)
    const int n_idx = l - m_idx * 10;
    const int m0 = m_idx * 128;
    const int n0 = n_idx * 64;

    const int t    = threadIdx.x;
    const int w    = t >> 6;
    const int lane = t & 63;
    const int quad = lane >> 4;
    const int ln   = lane & 15;

    f32x4 acc[2][4];
#pragma unroll
    for (int mi = 0; mi < 2; ++mi)
#pragma unroll
        for (int nt = 0; nt < 4; ++nt)
#pragma unroll
            for (int e = 0; e < 4; ++e) acc[mi][nt][e] = 0.f;

    const int lr = lane >> 2;
    const int lc = (lane & 3) * 8;

    auto stage = [&](int buf, int k0) {
        unsigned short* As = smem[buf];            // 128*32
        unsigned short* Bs = smem[buf] + 4096;     // 64*32
        const unsigned short* gp = Oh + (size_t)(m0 + w * 32 + lr) * DIM + k0 + lc;
#pragma unroll
        for (int i = 0; i < 2; ++i)
            dma16(gp + (size_t)i * 16 * DIM, &As[(w * 32 + i * 16) * 32]);
        const size_t gb = (size_t)(n0 + w * 16 + lr) * DIM + k0 + lc;
        dma16(Woh + gb, &Bs[w * 16 * 32]);
    };

    stage(0, 0);
    __syncthreads();

    for (int k0 = 0; k0 < DIM; k0 += 32) {
        const int kb = (k0 >> 5) & 1;
        if (k0 + 32 < DIM) stage(kb ^ 1, k0 + 32);

        const unsigned short* As = smem[kb];
        const unsigned short* Bs = smem[kb] + 4096;
        bf16x8 af[2];
#pragma unroll
        for (int mi = 0; mi < 2; ++mi)
            af[mi] = *(const bf16x8*)&As[(w * 32 + mi * 16 + ln) * 32 + quad * 8];
#pragma unroll
        for (int nt = 0; nt < 4; ++nt) {
            bf16x8 bh = *(const bf16x8*)&Bs[(nt * 16 + ln) * 32 + quad * 8];
#pragma unroll
            for (int mi = 0; mi < 2; ++mi)
                acc[mi][nt] = mfma16(af[mi], bh, acc[mi][nt]);
        }
        __syncthreads();
    }

#pragma unroll
    for (int mi = 0; mi < 2; ++mi)
#pragma unroll
        for (int r = 0; r < 4; ++r) {
            const size_t row = m0 + w * 32 + mi * 16 + quad * 4 + r;
#pragma unroll
            for (int nt = 0; nt < 4; ++nt) {
                const int col = n0 + nt * 16 + ln;
                out[row * DIM + col] = acc[mi][nt][r] + bo[col];
            }
        }
}

// ---------------------------------------------------------------------------
extern "C" void kernel_launch(void* const* d_in, const int* in_sizes, int n_in,
                              void* d_out, int out_size, void* d_ws, size_t ws_size,
                              hipStream_t stream)
{
    const float* x  = (const float*)d_in[0];
    const float* Wq = (const float*)d_in[1];
    const float* Wk = (const float*)d_in[2];
    const float* Wv = (const float*)d_in[3];
    const float* Wo = (const float*)d_in[4];
    const float* bo = (const float*)d_in[5];
    float* out = (float*)d_out;

    const size_t NX = (size_t)M_TOT * DIM;   // 4,423,680
    const size_t NW = (size_t)DIM * DIM;     // 409,600
    unsigned short* p = (unsigned short*)d_ws;
    unsigned short* Wqh = p;  p += NW;
    unsigned short* Wkh = p;  p += NW;
    unsigned short* Wvh = p;  p += NW;
    unsigned short* Woh = p;  p += NW;
    unsigned short* Xh  = p;  p += NX;
    unsigned short* Qhb = p;  p += NX;
    unsigned short* Kbb = p;  p += NX;
    unsigned short* Vtb = p;  p += NX;
    unsigned short* Ohb = Xh;                 // Xh dead after QKV GEMM

    // flash-decoding partials live in d_out (dead until oproj rewrites it)
    unsigned short* Pn = (unsigned short*)d_out;            // 16*576*640 bf16
    float2* ml = (float2*)((char*)d_out + (size_t)16 * SEQ * DIM * 2);

    split_kernel<<<dim3(1480), 256, 0, stream>>>(x, Wq, Wk, Wv, Wo,
        Xh, Wqh, Wkh, Wvh, Woh);

    dim3 g1(M_TOT / 128, DIM / 64, 3);
    qkv_mfma_kernel<<<g1, 256, 0, stream>>>(Xh, Wqh, Wkh, Wvh, Qhb, Kbb, Vtb);

    dim3 g2(3, HEADS, 20);
    attn_mfma_kernel<<<g2, 256, 0, stream>>>(Qhb, Kbb, Vtb, Ohb, Pn, ml);

    dim3 g3(SEQ, 8);
    merge_kernel<<<g3, 320, 0, stream>>>(Pn, ml, Ohb);

    dim3 g4(M_TOT / 128, DIM / 64);
    oproj_mfma_kernel<<<g4, 256, 0, stream>>>(Ohb, Woh, bo, out);
}

// Round 15
// 183.334 us; speedup vs baseline: 1.4284x; 1.0079x over previous
//
#include <hip/hip_runtime.h>
#include <hip/hip_bf16.h>

#define SEQ    576
#define DIM    640
#define HEADS  8
#define HD     80          // DIM / HEADS
#define NF     4
#define NB     12          // 3 * NF
#define M_TOT  (NB * SEQ)  // 6912
#define SCALE  0.11180339887498949f   // 1/sqrt(80)
#define LOG2E  1.4426950408889634f

// s_waitcnt immediates (gfx9 encoding: vmcnt[3:0]|[15:14], exp[6:4], lgkm[11:8])
#define WAIT_VM3   0x0F73   // vmcnt(3),  lgkm no-wait, exp no-wait
#define WAIT_VM0   0x0F70   // vmcnt(0),  lgkm no-wait
#define WAIT_LGKM0 0xC07F   // lgkmcnt(0), vmcnt no-wait

typedef __attribute__((ext_vector_type(8))) short          bf16x8;
typedef __attribute__((ext_vector_type(4))) float          f32x4;
typedef __attribute__((ext_vector_type(8))) unsigned short u16x8;
typedef __attribute__((ext_vector_type(4))) unsigned short u16x4;

__device__ __forceinline__ unsigned short f2bf(float x) {
    unsigned u = __float_as_uint(x);
    u += 0x7fffu + ((u >> 16) & 1u);
    return (unsigned short)(u >> 16);
}
__device__ __forceinline__ float bf2f(unsigned short h) {
    return __uint_as_float((unsigned)h << 16);
}
__device__ __forceinline__ f32x4 mfma16(bf16x8 a, bf16x8 b, f32x4 c) {
    return __builtin_amdgcn_mfma_f32_16x16x32_bf16(a, b, c, 0, 0, 0);
}
__device__ __forceinline__ float fexp2(float x) {
    return __builtin_amdgcn_exp2f(x);
}
__device__ __forceinline__ float max3f(float a, float b, float c) {
    return fmaxf(fmaxf(a, b), c);   // clang fuses to v_max3_f32
}
// async global->LDS DMA, 16B/lane, dest = lds base + lane*16
__device__ __forceinline__ void dma16(const void* g, void* s) {
    __builtin_amdgcn_global_load_lds(
        (const __attribute__((address_space(1))) void*)g,
        (__attribute__((address_space(3))) void*)s, 16, 0, 0);
}
// pinned raw barrier: waitcnt must be a literal -> template parameter
// (round-14 compile fail: function arg isn't an ICE for the builtin).
// sched_barrier(0) on both sides (rule 18).
template<int WC>
__device__ __forceinline__ void pinned_waitcnt_barrier() {
    __builtin_amdgcn_s_waitcnt(WC);
    __builtin_amdgcn_sched_barrier(0);
    __builtin_amdgcn_s_barrier();
    __builtin_amdgcn_sched_barrier(0);
}

// ---------------------------------------------------------------------------
// Convert fp32 -> bf16 (round-to-nearest). Compact flat grid of 1480 blocks
// (1080 for X + 4x100 for weights) — no no-op blocks.
// ---------------------------------------------------------------------------
__global__ __launch_bounds__(256) void split_kernel(
    const float* __restrict__ X,  const float* __restrict__ Wq,
    const float* __restrict__ Wk, const float* __restrict__ Wv,
    const float* __restrict__ Wo,
    unsigned short* __restrict__ Xh,  unsigned short* __restrict__ Wqh,
    unsigned short* __restrict__ Wkh, unsigned short* __restrict__ Wvh,
    unsigned short* __restrict__ Woh)
{
    const int b = blockIdx.x;
    const float* src; unsigned short* dh; int chunk; float s = 1.0f;
    if (b < 1080) {                       // X: 1080 * 4096 == M_TOT*DIM exactly
        src = X; dh = Xh; chunk = b;
    } else {
        const int wb = b - 1080;          // 0..399
        const int wsel = wb / 100;        // 0..3
        chunk = wb - wsel * 100;          // 0..99 (100*4096 == DIM*DIM)
        switch (wsel) {
            case 0:  src = Wq; dh = Wqh; s = SCALE * LOG2E; break;
            case 1:  src = Wk; dh = Wkh; break;
            case 2:  src = Wv; dh = Wvh; break;
            default: src = Wo; dh = Woh; break;
        }
    }
    const int base = chunk * 4096 + threadIdx.x * 16;
#pragma unroll
    for (int half = 0; half < 2; ++half) {
        const int bb = base + half * 8;
        float4 a4 = *(const float4*)(src + bb);
        float4 b4 = *(const float4*)(src + bb + 4);
        float vv[8] = {a4.x, a4.y, a4.z, a4.w, b4.x, b4.y, b4.z, b4.w};
        union { unsigned short u[8]; u16x8 v; } ph;
#pragma unroll
        for (int j = 0; j < 8; ++j) ph.u[j] = f2bf(vv[j] * s);
        *(u16x8*)(dh + bb) = ph.v;
    }
}

// ---------------------------------------------------------------------------
// QKV GEMM (single bf16). Tile 128(M) x 64(N), BK=32, block 256.
// grid=(54,10,3); z epilogue: 0 -> Qh, 1 -> Kb, 2 -> Vt transpose.
// Bijective XCD swizzle (1620 = 8*202+4), m-major.
// ROUND-25 (T3/T4, compile-fixed): counted-vmcnt 2-deep pipeline. The old
// __syncthreads() emitted s_waitcnt vmcnt(0) every iter, draining the
// just-issued prefetch DMA (m233: drain+barrier ~72% of a 2-phase loop).
// Keep 2 tiles in flight; per iter: compute buf -> lgkm(0)+barrier (all
// reads done) -> issue T(k+2) into it -> vmcnt(3) (T(k+1) landed; vmcnt
// retires in order) + barrier. Never vmcnt(0) in steady state.
// sched_barrier(0) pins every hand-placed sync (rule 18). Race audit:
// overwrite-guard = barrier#1; land-guard = counted vmcnt + barrier#2.
// ---------------------------------------------------------------------------
__global__ __launch_bounds__(256) void qkv_mfma_kernel(
    const unsigned short* __restrict__ Xh,
    const unsigned short* __restrict__ Wqh, const unsigned short* __restrict__ Wkh,
    const unsigned short* __restrict__ Wvh,
    unsigned short* __restrict__ Qh,
    unsigned short* __restrict__ Kb, unsigned short* __restrict__ VtG)
{
    __shared__ unsigned short smem[2][6144];    // 24 KB: A 128x32 + B 64x32 per buf

    // ---- XCD-aware bijective remap: 1620 blocks = 8*202 + 4 ----
    const int flat = blockIdx.x + 54 * (blockIdx.y + 10 * blockIdx.z);
    const int xcd  = flat & 7;
    const int slot = flat >> 3;                      // 0..202
    const int l    = (xcd < 4 ? xcd * 203 : 812 + (xcd - 4) * 202) + slot;
    const int m_idx = l / 30;                        // 0..53 (m-major: 30 tiles/panel)
    const int rem   = l - m_idx * 30;
    const int z     = rem / 10;                      // 0..2
    const int n_idx = rem - z * 10;                  // 0..9

    const unsigned short* WH = (z == 0) ? Wqh : ((z == 1) ? Wkh : Wvh);
    const int m0 = m_idx * 128;
    const int n0 = n_idx * 64;

    const int t    = threadIdx.x;
    const int w    = t >> 6;
    const int lane = t & 63;
    const int quad = lane >> 4;
    const int ln   = lane & 15;

    f32x4 acc[2][4];
#pragma unroll
    for (int mi = 0; mi < 2; ++mi)
#pragma unroll
        for (int nt = 0; nt < 4; ++nt)
#pragma unroll
            for (int e = 0; e < 4; ++e) acc[mi][nt][e] = 0.f;

    const int lr = lane >> 2;          // 0..15 (row within 16-row DMA chunk)
    const int lc = (lane & 3) * 8;     // 0,8,16,24 (shorts)

    // stage K-tile k0 into buffer buf (3 x 1KB DMA per wave)
    auto stage = [&](int buf, int k0) {
        unsigned short* As = smem[buf];            // 128*32
        unsigned short* Bs = smem[buf] + 4096;     // 64*32
        const unsigned short* gp = Xh + (size_t)(m0 + w * 32 + lr) * DIM + k0 + lc;
#pragma unroll
        for (int i = 0; i < 2; ++i)
            dma16(gp + (size_t)i * 16 * DIM, &As[(w * 32 + i * 16) * 32]);
        const size_t gb = (size_t)(n0 + w * 16 + lr) * DIM + k0 + lc;
        dma16(WH + gb, &Bs[w * 16 * 32]);
    };

    // ---- prologue: 2 tiles in flight; T0 landed for all waves ----
    stage(0, 0);
    stage(1, 32);
    pinned_waitcnt_barrier<WAIT_VM3>();    // own T0 (3 DMAs) retired; join

    for (int k = 0; k < 20; ++k) {
        const int kb = k & 1;
        const unsigned short* As = smem[kb];
        const unsigned short* Bs = smem[kb] + 4096;
        bf16x8 af[2];
#pragma unroll
        for (int mi = 0; mi < 2; ++mi)
            af[mi] = *(const bf16x8*)&As[(w * 32 + mi * 16 + ln) * 32 + quad * 8];
#pragma unroll
        for (int nt = 0; nt < 4; ++nt) {
            bf16x8 bh = *(const bf16x8*)&Bs[(nt * 16 + ln) * 32 + quad * 8];
#pragma unroll
            for (int mi = 0; mi < 2; ++mi)
                acc[mi][nt] = mfma16(af[mi], bh, acc[mi][nt]);
        }
        // all waves done reading buf kb (own lgkm drained, then join)
        pinned_waitcnt_barrier<WAIT_LGKM0>();
        if (k + 2 < 20) {
            stage(kb, (k + 2) * 32);               // T(k+2) -> buf kb
            pinned_waitcnt_barrier<WAIT_VM3>();    // T(k+1) landed (in-order)
        } else {
            pinned_waitcnt_barrier<WAIT_VM0>();    // tail: drain remaining
        }
    }

    if (z == 0) {
#pragma unroll
        for (int mi = 0; mi < 2; ++mi)
#pragma unroll
            for (int r = 0; r < 4; ++r) {
                const size_t row = m0 + w * 32 + mi * 16 + quad * 4 + r;
#pragma unroll
                for (int nt = 0; nt < 4; ++nt)
                    Qh[row * DIM + n0 + nt * 16 + ln] = f2bf(acc[mi][nt][r]);
            }
    } else if (z == 1) {
#pragma unroll
        for (int mi = 0; mi < 2; ++mi)
#pragma unroll
            for (int r = 0; r < 4; ++r) {
                const size_t row = m0 + w * 32 + mi * 16 + quad * 4 + r;
#pragma unroll
                for (int nt = 0; nt < 4; ++nt)
                    Kb[row * DIM + n0 + nt * 16 + ln] = f2bf(acc[mi][nt][r]);
            }
    } else {
        // transpose 128x64 -> Vt[64 n][128 m] via LDS (single pass, 4 waves)
        unsigned short* Vts = smem[0];   // 64 x 136 = 8704 shorts <= 12288 avail
        // loop exits through a full barrier: all smem reads complete
#pragma unroll
        for (int mi = 0; mi < 2; ++mi)
#pragma unroll
            for (int nt = 0; nt < 4; ++nt)
#pragma unroll
                for (int r = 0; r < 4; ++r)
                    Vts[(nt * 16 + ln) * 136 + w * 32 + mi * 16 + quad * 4 + r] =
                        f2bf(acc[mi][nt][r]);
        __syncthreads();
        const int nn = t & 63;
        const int c0 = (t >> 6) * 32;
#pragma unroll
        for (int i = 0; i < 4; ++i)
            *(u16x8*)(VtG + (size_t)(n0 + nn) * M_TOT + m0 + c0 + i * 8) =
                *(const u16x8*)&Vts[nn * 136 + c0 + i * 8];
    }
}

// ---------------------------------------------------------------------------
// Flash attention v15 (round-19 structure, UNCHANGED — converged at ~54 us;
// all pipes <31%; block-split/fusion levers measurably regress; round-22's
// device-scope __threadfence() destroyed L2 locality — never fuse here).
// grid=(3,8,20), block 256 (4 waves x 48 q-rows). 2x18 cross split.
// Inner loop: P never touches LDS (sigma-permuted K staging); O^T PV;
// per-lane rescale/epilogue; defer-max; zero bank conflicts; K dbuf via
// DMA; V dbuf via reg-stage; l computed INSIDE PV MFMA via ones-row 80.
// NOTE: never leave MFMA-read LDS uninitialized — 0*NaN = NaN.
// z<16: cross chunk -> partials (Pn,ml); z>=16: self frame -> Oh.
// ---------------------------------------------------------------------------
__global__ __launch_bounds__(256, 2) void attn_mfma_kernel(
    const unsigned short* __restrict__ Qh,
    const unsigned short* __restrict__ Kb, const unsigned short* __restrict__ Vt,
    unsigned short* __restrict__ Oh,
    unsigned short* __restrict__ Pn, float2* __restrict__ ml)
{
    // ---- XCD-aware remap: one head per XCD (480 = 8*60, bijective) ----
    const int flat = blockIdx.x + 3 * (blockIdx.y + 8 * blockIdx.z);
    const int h    = flat & 7;          // head = XCD
    const int slot = flat >> 3;         // 0..59
    const int z    = slot / 3;          // 0..19
    const int qt   = slot - z * 3;      // 0..2

    int f, kbase, nkt, idx = -1;
    if (z < 16) {
        idx = z;
        const int fi = z >> 1;
        f = 4 + fi;
        kbase = ((fi < 4 ? 4 : 8) + (z & 1) * 2) * SEQ;
        nkt = 18;
    } else {
        f = z - 16;
        kbase = f * SEQ;
        nkt = 9;
    }

    const int t    = threadIdx.x;
    const int w    = t >> 6;
    const int lane = t & 63;
    const int quad = lane >> 4;
    const int ln   = lane & 15;

    __shared__ unsigned short KhS[2][12 * 64 * 8]; // 24,576 B, sigma-permuted
    __shared__ unsigned short VtS[2][96 * 64];     // 24,576 B: 80 V rows + ones/zero group

    // sigma^-1: staging lane -> physical key offset within the 64-key tile
    const int klane = (lane & 3) | (((lane >> 4) & 1) << 2) |
                      (((lane >> 2) & 3) << 3) | (lane & 32);

    // staging helpers -------------------------------------------------------
    auto stage_k = [&](int buf, int kvt) {
        const unsigned short* kg = Kb + (size_t)(kbase + kvt * 64) * DIM + h * HD;
#pragma unroll
        for (int rnd = 0; rnd < 3; ++rnd) {
            const int g = rnd * 4 + w;          // d-colgroup 0..11
            dma16(kg + (size_t)klane * DIM + g * 8, &KhS[buf][g * 512]);
        }
    };
    u16x8 vreg[3];
    auto load_v = [&](int kvt) {
#pragma unroll
        for (int i = 0; i < 3; ++i) {
            const int u = t + i * 256;
            if (u < 640) {
                const int d = u >> 3, c8 = u & 7;
                vreg[i] = *(const u16x8*)(Vt + (size_t)(h * HD + d) * M_TOT +
                                          kbase + kvt * 64 + c8 * 8);
            }
        }
    };
    auto write_v = [&](int buf) {
#pragma unroll
        for (int i = 0; i < 3; ++i) {
            const int u = t + i * 256;
            if (u < 640) {
                const int d = u >> 3, c8 = u & 7;
                const int c8s = (c8 + 3 * d) & 7;
                *(u16x8*)&VtS[buf][d * 64 + c8s * 8] = vreg[i];
            }
        }
    };

    // ---- prologue part 1: issue tile-0 staging FIRST (latency in flight) ----
    stage_k(0, 0);
    load_v(0);

    // ---- ones/zero rows 80..95 of both V buffers (once) ----
    {
        const int buf = t >> 7;                  // 0..1
        const int c   = t & 127;                 // chunk within buffer
        const int row = 80 + (c >> 3);
        const unsigned short val = (row == 80) ? (unsigned short)0x3F80 : (unsigned short)0;
        union { unsigned short u[8]; u16x8 v; } fill;
#pragma unroll
        for (int j = 0; j < 8; ++j) fill.u[j] = val;
        *(u16x8*)&VtS[buf][row * 64 + (c & 7) * 8] = fill.v;
    }

    // ---- Q fragments (B-operand of S^T) — overlap with staging latency ----
    bf16x8 qf[3][3];
#pragma unroll
    for (int mi = 0; mi < 3; ++mi) {
        const int qrow = f * SEQ + qt * 192 + w * 48 + mi * 16 + ln;
        const unsigned short* qp = Qh + (size_t)qrow * DIM + h * HD;
#pragma unroll
        for (int kc = 0; kc < 3; ++kc) {
            const int dbase = kc * 32 + quad * 8;
            if (dbase < HD) {
                qf[mi][kc] = *(const bf16x8*)(qp + dbase);
            } else {
                union { unsigned short u[8]; bf16x8 v; } zz;
#pragma unroll
                for (int j = 0; j < 8; ++j) zz.u[j] = 0;
                qf[mi][kc] = zz.v;
            }
        }
    }

    // per-lane running max for q = mi*16 + ln (replicated across quads)
    float m_[3];
#pragma unroll
    for (int mi = 0; mi < 3; ++mi) m_[mi] = -INFINITY;

    // oacc is O^T: lane(ln,quad) reg r holds O[q=mi*16+ln][d=nt*16+quad*4+r];
    // nt=5 is the l-row group (meaningful value at quad==0, r==0).
    f32x4 oacc[3][6];
#pragma unroll
    for (int mi = 0; mi < 3; ++mi)
#pragma unroll
        for (int nt = 0; nt < 6; ++nt)
#pragma unroll
            for (int e = 0; e < 4; ++e) oacc[mi][nt][e] = 0.f;

    // ---- prologue part 2: land V, then barrier ----
    write_v(0);          // compiler waits vmcnt for vreg before ds_write
    __syncthreads();     // vmcnt(0): K-DMA landed; lgkm(0): V + fill visible

    for (int kt = 0; kt < nkt; ++kt) {
        const int cur = kt & 1;
        const bool pf = (kt + 1 < nkt);

        // ---- prefetch next tile: issue loads, keep in flight ----
        if (pf) {
            load_v(kt + 1);            // global->reg, vmcnt in flight
            stage_k(cur ^ 1, kt + 1);  // global->LDS DMA, vmcnt in flight
        }

        // ---- S^T = K.Q^T (zero-C first MFMA; sigma-permuted key rows) ----
        const f32x4 fz = {0.f, 0.f, 0.f, 0.f};
        f32x4 sacc[3][4];
#pragma unroll
        for (int nt = 0; nt < 4; ++nt) {
            const int ks = ln + 16 * (nt >> 1) + 32 * (nt & 1);
#pragma unroll
            for (int kc = 0; kc < 3; ++kc) {
                bf16x8 kf = *(const bf16x8*)&KhS[cur][((kc * 4 + quad) * 64 + ks) * 8];
#pragma unroll
                for (int mi = 0; mi < 3; ++mi)
                    sacc[mi][nt] = (kc == 0)
                        ? mfma16(kf, qf[mi][0], fz)
                        : mfma16(kf, qf[mi][kc], sacc[mi][nt]);  // swapped!
            }
        }

        // ---- softmax: max3 trees, defer-max (l handled by PV's l-row) ----
        float mxl[3];
#pragma unroll
        for (int mi = 0; mi < 3; ++mi) {
            const f32x4* S = sacc[mi];
            const float a = max3f(S[0][0], S[0][1], S[0][2]);
            const float b = max3f(S[0][3], S[1][0], S[1][1]);
            const float c = max3f(S[1][2], S[1][3], S[2][0]);
            const float d = max3f(S[2][1], S[2][2], S[2][3]);
            const float e = max3f(S[3][0], S[3][1], S[3][2]);
            mxl[mi] = fmaxf(max3f(a, b, c), max3f(d, e, S[3][3]));
        }
        const bool need = (mxl[0] > m_[0] + 8.0f) || (mxl[1] > m_[1] + 8.0f) ||
                          (mxl[2] > m_[2] + 8.0f);
        if (__any(need)) {           // wave-uniform slow path (rare)
#pragma unroll
            for (int mi = 0; mi < 3; ++mi) {
                float mx = fmaxf(mxl[mi], __shfl_xor(mxl[mi], 16));
                mx = fmaxf(mx, __shfl_xor(mx, 32));
                const float mnew = fmaxf(m_[mi], mx);
                const float aq = fexp2(m_[mi] - mnew);
                m_[mi] = mnew;
                // O^T layout: q = ln per-lane -> rescale needs NO shuffles;
                // nt=5 (l-row) rescaled too == old l_*=aq.
#pragma unroll
                for (int nt = 0; nt < 6; ++nt)
#pragma unroll
                    for (int e = 0; e < 4; ++e) oacc[mi][nt][e] *= aq;
            }
        }
        // ---- exp + pack straight into PV B-frags (NO LDS round-trip) ----
        bf16x8 pfv[3][2];
#pragma unroll
        for (int mi = 0; mi < 3; ++mi) {
            float p[4][4];
#pragma unroll
            for (int nt = 0; nt < 4; ++nt) {
#pragma unroll
                for (int r = 0; r < 4; ++r)
                    p[nt][r] = fexp2(sacc[mi][nt][r] - m_[mi]);
            }
            union { unsigned w[4]; bf16x8 v; } u0, u1;
            u0.w[0] = __builtin_amdgcn_perm(__float_as_uint(p[0][1]),
                                            __float_as_uint(p[0][0]), 0x07060302u);
            u0.w[1] = __builtin_amdgcn_perm(__float_as_uint(p[0][3]),
                                            __float_as_uint(p[0][2]), 0x07060302u);
            u0.w[2] = __builtin_amdgcn_perm(__float_as_uint(p[2][1]),
                                            __float_as_uint(p[2][0]), 0x07060302u);
            u0.w[3] = __builtin_amdgcn_perm(__float_as_uint(p[2][3]),
                                            __float_as_uint(p[2][2]), 0x07060302u);
            u1.w[0] = __builtin_amdgcn_perm(__float_as_uint(p[1][1]),
                                            __float_as_uint(p[1][0]), 0x07060302u);
            u1.w[1] = __builtin_amdgcn_perm(__float_as_uint(p[1][3]),
                                            __float_as_uint(p[1][2]), 0x07060302u);
            u1.w[2] = __builtin_amdgcn_perm(__float_as_uint(p[3][1]),
                                            __float_as_uint(p[3][0]), 0x07060302u);
            u1.w[3] = __builtin_amdgcn_perm(__float_as_uint(p[3][3]),
                                            __float_as_uint(p[3][2]), 0x07060302u);
            pfv[mi][0] = u0.v;
            pfv[mi][1] = u1.v;
        }

        // ---- O^T += V^T.P : A = V^T from VtS (incl. l-row nt=5), B = pfv ----
#pragma unroll
        for (int kc = 0; kc < 2; ++kc)
#pragma unroll
            for (int nt = 0; nt < 6; ++nt) {
                const int vrow = nt * 16 + ln;
                const int c8r  = ((kc * 4 + quad) + 3 * vrow) & 7;
                bf16x8 vf = *(const bf16x8*)&VtS[cur][vrow * 64 + c8r * 8];
#pragma unroll
                for (int mi = 0; mi < 3; ++mi)
                    oacc[mi][nt] = mfma16(vf, pfv[mi][kc], oacc[mi][nt]);
            }

        // ---- land prefetched V into the other buffer, then barrier ----
        if (pf) write_v(cur ^ 1);
        __syncthreads();   // vmcnt(0): next K-DMA landed; all reads of cur done
    }

    // ---- epilogue: l lives in oacc[mi][5][0] at quad==0 (lanes 0..15);
    //      broadcast to all quads with one shuffle per mi. ----
#pragma unroll
    for (int mi = 0; mi < 3; ++mi) {
        const float lsum = __shfl(oacc[mi][5][0], ln, 64);
        const float inv = 1.f / lsum;
        const int rr = qt * 192 + w * 48 + mi * 16 + ln;    // frame-local q-row
#pragma unroll
        for (int nt = 0; nt < 5; ++nt) {
            union { unsigned short u[4]; u16x4 v; } o4;
#pragma unroll
            for (int r = 0; r < 4; ++r) o4.u[r] = f2bf(oacc[mi][nt][r] * inv);
            const int dcol = h * HD + nt * 16 + quad * 4;
            if (idx < 0)
                *(u16x4*)&Oh[((size_t)f * SEQ + rr) * DIM + dcol] = o4.v;
            else
                *(u16x4*)&Pn[((size_t)idx * SEQ + rr) * DIM + dcol] = o4.v;
        }
    }
    if (idx >= 0 && lane < 16) {
#pragma unroll
        for (int mi = 0; mi < 3; ++mi) {
            const int rr = qt * 192 + w * 48 + mi * 16 + lane;
            ml[((size_t)idx * 8 + h) * SEQ + rr] =
                make_float2(m_[mi], oacc[mi][5][0]);   // lane<16 == quad 0
        }
    }
}

// ---------------------------------------------------------------------------
// Merge the two partials of each cross frame. grid=(576,8), block 320.
// ---------------------------------------------------------------------------
__global__ __launch_bounds__(320) void merge_kernel(
    const unsigned short* __restrict__ Pn, const float2* __restrict__ ml,
    unsigned short* __restrict__ Oh)
{
    const int row = blockIdx.x;   // 0..575
    const int fi  = blockIdx.y;   // 0..7
    const int t   = threadIdx.x;  // 0..319
    const int i0  = fi * 2, i1 = i0 + 1;
#pragma unroll
    for (int rep = 0; rep < 2; ++rep) {
        const int col = t + rep * 320;
        const int h = col / 80;
        const float2 a = ml[((size_t)i0 * 8 + h) * SEQ + row];
        const float2 b = ml[((size_t)i1 * 8 + h) * SEQ + row];
        const float M  = fmaxf(a.x, b.x);
        const float w0 = fexp2(a.x - M) * a.y;
        const float w1 = fexp2(b.x - M) * b.y;
        const float inv = 1.f / (w0 + w1);
        const float p0 = bf2f(Pn[((size_t)i0 * SEQ + row) * DIM + col]);
        const float p1 = bf2f(Pn[((size_t)i1 * SEQ + row) * DIM + col]);
        Oh[((size_t)(4 + fi) * SEQ + row) * DIM + col] = f2bf((w0 * p0 + w1 * p1) * inv);
    }
}

// ---------------------------------------------------------------------------
// Output projection: out = Oh * Wo^T + bo (single bf16), fp32 out.
// Tile 128x64, grid (54,10) = 540 blocks. BK=32, global_load_lds staging,
// bijective XCD swizzle (540 = 8*67 + 4).
// ROUND-25: same counted-vmcnt 2-deep pipeline as qkv.
// ---------------------------------------------------------------------------
__global__ __launch_bounds__(256) void oproj_mfma_kernel(
    const unsigned short* __restrict__ Oh,
    const unsigned short* __restrict__ Woh,
    const float* __restrict__ bo, float* __restrict__ out)
{
    __shared__ unsigned short smem[2][6144];    // 24 KB

    // ---- XCD-aware bijective remap: 540 blocks = 8*67 + 4 ----
    const int flat = blockIdx.x + 54 * blockIdx.y;
    const int xcd  = flat & 7;
    const int slot = flat >> 3;
    const int l    = (xcd < 4 ? xcd * 68 : 272 + (xcd - 4) * 67) + slot;
    const int m_idx = l / 10;                        // 0..53 (m-major)
    const int n_idx = l - m_idx * 10;
    const int m0 = m_idx * 128;
    const int n0 = n_idx * 64;

    const int t    = threadIdx.x;
    const int w    = t >> 6;
    const int lane = t & 63;
    const int quad = lane >> 4;
    const int ln   = lane & 15;

    f32x4 acc[2][4];
#pragma unroll
    for (int mi = 0; mi < 2; ++mi)
#pragma unroll
        for (int nt = 0; nt < 4; ++nt)
#pragma unroll
            for (int e = 0; e < 4; ++e) acc[mi][nt][e] = 0.f;

    const int lr = lane >> 2;
    const int lc = (lane & 3) * 8;

    auto stage = [&](int buf, int k0) {
        unsigned short* As = smem[buf];            // 128*32
        unsigned short* Bs = smem[buf] + 4096;     // 64*32
        const unsigned short* gp = Oh + (size_t)(m0 + w * 32 + lr) * DIM + k0 + lc;
#pragma unroll
        for (int i = 0; i < 2; ++i)
            dma16(gp + (size_t)i * 16 * DIM, &As[(w * 32 + i * 16) * 32]);
        const size_t gb = (size_t)(n0 + w * 16 + lr) * DIM + k0 + lc;
        dma16(Woh + gb, &Bs[w * 16 * 32]);
    };

    // ---- prologue: 2 tiles in flight; T0 landed for all waves ----
    stage(0, 0);
    stage(1, 32);
    pinned_waitcnt_barrier<WAIT_VM3>();

    for (int k = 0; k < 20; ++k) {
        const int kb = k & 1;
        const unsigned short* As = smem[kb];
        const unsigned short* Bs = smem[kb] + 4096;
        bf16x8 af[2];
#pragma unroll
        for (int mi = 0; mi < 2; ++mi)
            af[mi] = *(const bf16x8*)&As[(w * 32 + mi * 16 + ln) * 32 + quad * 8];
#pragma unroll
        for (int nt = 0; nt < 4; ++nt) {
            bf16x8 bh = *(const bf16x8*)&Bs[(nt * 16 + ln) * 32 + quad * 8];
#pragma unroll
            for (int mi = 0; mi < 2; ++mi)
                acc[mi][nt] = mfma16(af[mi], bh, acc[mi][nt]);
        }
        pinned_waitcnt_barrier<WAIT_LGKM0>();      // all reads of buf kb done
        if (k + 2 < 20) {
            stage(kb, (k + 2) * 32);               // T(k+2) -> buf kb
            pinned_waitcnt_barrier<WAIT_VM3>();    // T(k+1) landed
        } else {
            pinned_waitcnt_barrier<WAIT_VM0>();
        }
    }

#pragma unroll
    for (int mi = 0; mi < 2; ++mi)
#pragma unroll
        for (int r = 0; r < 4; ++r) {
            const size_t row = m0 + w * 32 + mi * 16 + quad * 4 + r;
#pragma unroll
            for (int nt = 0; nt < 4; ++nt) {
                const int col = n0 + nt * 16 + ln;
                out[row * DIM + col] = acc[mi][nt][r] + bo[col];
            }
        }
}

// ---------------------------------------------------------------------------
extern "C" void kernel_launch(void* const* d_in, const int* in_sizes, int n_in,
                              void* d_out, int out_size, void* d_ws, size_t ws_size,
                              hipStream_t stream)
{
    const float* x  = (const float*)d_in[0];
    const float* Wq = (const float*)d_in[1];
    const float* Wk = (const float*)d_in[2];
    const float* Wv = (const float*)d_in[3];
    const float* Wo = (const float*)d_in[4];
    const float* bo = (const float*)d_in[5];
    float* out = (float*)d_out;

    const size_t NX = (size_t)M_TOT * DIM;   // 4,423,680
    const size_t NW = (size_t)DIM * DIM;     // 409,600
    unsigned short* p = (unsigned short*)d_ws;
    unsigned short* Wqh = p;  p += NW;
    unsigned short* Wkh = p;  p += NW;
    unsigned short* Wvh = p;  p += NW;
    unsigned short* Woh = p;  p += NW;
    unsigned short* Xh  = p;  p += NX;
    unsigned short* Qhb = p;  p += NX;
    unsigned short* Kbb = p;  p += NX;
    unsigned short* Vtb = p;  p += NX;
    unsigned short* Ohb = Xh;                 // Xh dead after QKV GEMM

    // flash-decoding partials live in d_out (dead until oproj rewrites it)
    unsigned short* Pn = (unsigned short*)d_out;            // 16*576*640 bf16
    float2* ml = (float2*)((char*)d_out + (size_t)16 * SEQ * DIM * 2);

    split_kernel<<<dim3(1480), 256, 0, stream>>>(x, Wq, Wk, Wv, Wo,
        Xh, Wqh, Wkh, Wvh, Woh);

    dim3 g1(M_TOT / 128, DIM / 64, 3);
    qkv_mfma_kernel<<<g1, 256, 0, stream>>>(Xh, Wqh, Wkh, Wvh, Qhb, Kbb, Vtb);

    dim3 g2(3, HEADS, 20);
    attn_mfma_kernel<<<g2, 256, 0, stream>>>(Qhb, Kbb, Vtb, Ohb, Pn, ml);

    dim3 g3(SEQ, 8);
    merge_kernel<<<g3, 320, 0, stream>>>(Pn, ml, Ohb);

    dim3 g4(M_TOT / 128, DIM / 64);
    oproj_mfma_kernel<<<g4, 256, 0, stream>>>(Ohb, Woh, bo, out);
}